// Round 1
// baseline (12915.729 us; speedup 1.0000x reference)
//
#include <hip/hip_runtime.h>
#include <hip/hip_fp16.h>

// BilinearAttention: context = softmax(mask? -1e9 : Q@K) @ V
// B=16, Tq=Tk=2048, D=1024, all fp32. Round 1: correct fp32 VALU flash
// attention. BQ=64 q-rows/workgroup, 512 threads, O accum in regs (128/thr).

#define B_   16
#define TQ   2048
#define TK   2048
#define DH   1024
#define BQ   64      // q-rows per workgroup
#define BT   128     // t-tile width
#define DCQ  32      // d-chunk for QK staging
#define VDC  64      // d-chunk for PV staging
#define NTHR 512
#define NEG_INF_ -1.0e9f

// ---------------- mask dtype detection -----------------------------------
// jnp.bool_ mask may arrive as int32 {0,1}, float32 {0.0,1.0}, or raw bytes.
// Sample 4096 words (16 KB, safe: mask buffer >= 67 MB in any format).
// flag: 0 = int32, 1 = float32, 2 = uint8 bytes.
__global__ void detect_mask_kernel(const void* __restrict__ mask, int* flag_out) {
    const int tid = threadIdx.x;
    const int*   mi = (const int*)mask;
    const float* mf = (const float*)mask;
    int ok_i = 1, ok_f = 1;
    for (int k = 0; k < 16; ++k) {
        int idx = tid * 16 + k;
        int iv = mi[idx];
        ok_i &= ((iv == 0) | (iv == 1));
        float fv = mf[idx];
        ok_f &= ((fv == 0.0f) | (fv == 1.0f));
    }
    int all_i = __syncthreads_and(ok_i);
    int all_f = __syncthreads_and(ok_f);
    if (tid == 0) flag_out[0] = all_i ? 0 : (all_f ? 1 : 2);
}

// ---------------- flash attention kernel ---------------------------------
// LDS: QK staging (Qt transposed + Kc) unioned with PV staging (Vc) since the
// phases are barrier-separated. Total ~61 KB -> 2 workgroups/CU.
union QKVSm {
    struct { float qt[DCQ][BQ + 2];    // [d][q] transposed, row 264B (8B-align for float2)
             float kc[DCQ][BT + 4]; } qk;  // [d][t], row 528B (16B-align for float4)
    struct { float vc[BT][VDC + 4]; } pv;  // [t][d], row 272B (16B-align)
};

__global__ __launch_bounds__(NTHR, 4)
void flash_attn_kernel(const float* __restrict__ Q, const float* __restrict__ K,
                       const float* __restrict__ V, const void* __restrict__ Mask,
                       const int* __restrict__ flagp, float* __restrict__ Out) {
    __shared__ QKVSm sm;
    __shared__ __half ps[BT][BQ + 2];    // P tile [t][q], row 132B (4B-align for half2)
    __shared__ float mred[BQ][17];
    __shared__ float sred[BQ][17];
    __shared__ float m_s[BQ], alpha_s[BQ], l_s[BQ];

    const int tid  = threadIdx.x;
    const int qblk = blockIdx.x, b = blockIdx.y;
    const int q0   = qblk * BQ;
    const int qy   = tid >> 4;    // 0..31 -> owns q rows 2qy, 2qy+1
    const int tx   = tid & 15;    // 0..15 -> t-group (QK) / d-group (PV)
    const int flag = flagp[0];

    float o[2][16][4];            // O accum: [qpair][dchunk][4] = 128 regs
#pragma unroll
    for (int i = 0; i < 2; ++i)
#pragma unroll
        for (int c = 0; c < 16; ++c)
#pragma unroll
            for (int k = 0; k < 4; ++k) o[i][c][k] = 0.0f;

    if (tid < BQ) { m_s[tid] = -3.0e38f; l_s[tid] = 0.0f; }
    __syncthreads();

    const float* Qb = Q + (size_t)(b * TQ + q0) * DH;
    const float* Kb = K + (size_t)b * DH * TK;
    const float* Vb = V + (size_t)b * TK * DH;

    for (int t0 = 0; t0 < TK; t0 += BT) {
        // ---------------- QK: S-tile [BQ x BT] over D -------------------
        float s[2][8];
#pragma unroll
        for (int i = 0; i < 2; ++i)
#pragma unroll
            for (int j = 0; j < 8; ++j) s[i][j] = 0.0f;

        for (int dc = 0; dc < DH; dc += DCQ) {
            __syncthreads();
            {   // stage Qt transposed: thread loads float4 along d, scatters
                int qq = tid >> 3, dg = tid & 7;
                float4 qv = *(const float4*)(Qb + (size_t)qq * DH + dc + dg * 4);
                sm.qk.qt[dg * 4 + 0][qq] = qv.x;
                sm.qk.qt[dg * 4 + 1][qq] = qv.y;
                sm.qk.qt[dg * 4 + 2][qq] = qv.z;
                sm.qk.qt[dg * 4 + 3][qq] = qv.w;
            }
            {   // stage Kc natural [d][t]: K is [B, D, Tk] so rows coalesce
                int d = tid >> 4, tg = tid & 15;
                const float* krow = Kb + (size_t)(dc + d) * TK + t0;
                *(float4*)&sm.qk.kc[d][tg * 4]      = *(const float4*)(krow + tg * 4);
                *(float4*)&sm.qk.kc[d][64 + tg * 4] = *(const float4*)(krow + 64 + tg * 4);
            }
            __syncthreads();
#pragma unroll
            for (int dd = 0; dd < DCQ; ++dd) {
                float2 a  = *(const float2*)&sm.qk.qt[dd][2 * qy];
                float4 k0 = *(const float4*)&sm.qk.kc[dd][tx * 8];
                float4 k1 = *(const float4*)&sm.qk.kc[dd][tx * 8 + 4];
                float kb[8] = {k0.x, k0.y, k0.z, k0.w, k1.x, k1.y, k1.z, k1.w};
#pragma unroll
                for (int j = 0; j < 8; ++j) {
                    s[0][j] += a.x * kb[j];
                    s[1][j] += a.y * kb[j];
                }
            }
        }

        // ---------------- mask + online softmax -------------------------
        const int trow = t0 + tx * 8;
#pragma unroll
        for (int i = 0; i < 2; ++i) {
            const int q = q0 + 2 * qy + i;
            const size_t base = (size_t)(b * TQ + q) * TK + trow;
            bool mk[8];
            if (flag == 0) {
                int4 u0 = *(const int4*)((const int*)Mask + base);
                int4 u1 = *(const int4*)((const int*)Mask + base + 4);
                mk[0] = u0.x != 0; mk[1] = u0.y != 0; mk[2] = u0.z != 0; mk[3] = u0.w != 0;
                mk[4] = u1.x != 0; mk[5] = u1.y != 0; mk[6] = u1.z != 0; mk[7] = u1.w != 0;
            } else if (flag == 1) {
                float4 f0 = *(const float4*)((const float*)Mask + base);
                float4 f1 = *(const float4*)((const float*)Mask + base + 4);
                mk[0] = f0.x != 0.f; mk[1] = f0.y != 0.f; mk[2] = f0.z != 0.f; mk[3] = f0.w != 0.f;
                mk[4] = f1.x != 0.f; mk[5] = f1.y != 0.f; mk[6] = f1.z != 0.f; mk[7] = f1.w != 0.f;
            } else {
                uint2 uv = *(const uint2*)((const unsigned char*)Mask + base);
#pragma unroll
                for (int k = 0; k < 4; ++k) {
                    mk[k]     = ((uv.x >> (8 * k)) & 0xffu) != 0;
                    mk[4 + k] = ((uv.y >> (8 * k)) & 0xffu) != 0;
                }
            }
            float mx = -3.0e38f;
#pragma unroll
            for (int j = 0; j < 8; ++j) {
                if (mk[j]) s[i][j] = NEG_INF_;
                mx = fmaxf(mx, s[i][j]);
            }
            mred[2 * qy + i][tx] = mx;
        }
        __syncthreads();
        if (tid < BQ) {
            float m = mred[tid][0];
#pragma unroll
            for (int k = 1; k < 16; ++k) m = fmaxf(m, mred[tid][k]);
            float mo = m_s[tid];
            float mn = fmaxf(mo, m);
            m_s[tid] = mn;
            alpha_s[tid] = __expf(mo - mn);   // exp(-3e38-mn) -> 0 on first tile
        }
        __syncthreads();
#pragma unroll
        for (int i = 0; i < 2; ++i) {
            const int q = 2 * qy + i;
            const float mn = m_s[q];
            float sum = 0.0f;
#pragma unroll
            for (int j = 0; j < 8; ++j) {
                float p = __expf(s[i][j] - mn);
                ps[tx * 8 + j][q] = __float2half(p);  // p in [0,1]: fp16 safe
                sum += p;
            }
            sred[q][tx] = sum;
        }
        __syncthreads();
        if (tid < BQ) {
            float sum = 0.0f;
#pragma unroll
            for (int k = 0; k < 16; ++k) sum += sred[tid][k];
            l_s[tid] = l_s[tid] * alpha_s[tid] + sum;
        }

        // ---------------- rescale O, then PV ----------------------------
        {
            float a0 = alpha_s[2 * qy], a1 = alpha_s[2 * qy + 1];
#pragma unroll
            for (int c = 0; c < 16; ++c)
#pragma unroll
                for (int k = 0; k < 4; ++k) { o[0][c][k] *= a0; o[1][c][k] *= a1; }
        }
#pragma unroll
        for (int vchunk = 0; vchunk < 16; ++vchunk) {
            __syncthreads();   // also protects ps/union reuse ordering
            {   // stage Vc [t][d] for d-range [vchunk*64, +64)
                int tv = tid >> 2, dg = tid & 3;
                const float* vrow = Vb + (size_t)(t0 + tv) * DH + vchunk * VDC + dg * 16;
#pragma unroll
                for (int k = 0; k < 4; ++k)
                    *(float4*)&sm.pv.vc[tv][dg * 16 + k * 4] = *(const float4*)(vrow + k * 4);
            }
            __syncthreads();
#pragma unroll 4
            for (int t = 0; t < BT; ++t) {
                float4 v = *(const float4*)&sm.pv.vc[t][tx * 4];
                __half2 ph = *(const __half2*)&ps[t][2 * qy];
                float p0 = __half2float(ph.x), p1 = __half2float(ph.y);
                o[0][vchunk][0] += p0 * v.x; o[0][vchunk][1] += p0 * v.y;
                o[0][vchunk][2] += p0 * v.z; o[0][vchunk][3] += p0 * v.w;
                o[1][vchunk][0] += p1 * v.x; o[1][vchunk][1] += p1 * v.y;
                o[1][vchunk][2] += p1 * v.z; o[1][vchunk][3] += p1 * v.w;
            }
        }
    }

    // ---------------- normalize + store ----------------------------------
    __syncthreads();
    float inv[2] = {1.0f / l_s[2 * qy], 1.0f / l_s[2 * qy + 1]};
#pragma unroll
    for (int i = 0; i < 2; ++i) {
        float* orow = Out + (size_t)(b * TQ + q0 + 2 * qy + i) * DH;
#pragma unroll
        for (int c = 0; c < 16; ++c) {
            float4 w = make_float4(o[i][c][0] * inv[i], o[i][c][1] * inv[i],
                                   o[i][c][2] * inv[i], o[i][c][3] * inv[i]);
            *(float4*)(orow + c * 64 + tx * 4) = w;
        }
    }
}

extern "C" void kernel_launch(void* const* d_in, const int* in_sizes, int n_in,
                              void* d_out, int out_size, void* d_ws, size_t ws_size,
                              hipStream_t stream) {
    const float* q    = (const float*)d_in[0];
    const float* k    = (const float*)d_in[1];
    const float* v    = (const float*)d_in[2];
    const void*  mask = d_in[3];
    float* out = (float*)d_out;
    int* flag = (int*)d_ws;   // only 4 bytes of ws used

    hipLaunchKernelGGL(detect_mask_kernel, dim3(1), dim3(256), 0, stream, mask, flag);
    dim3 grid(TQ / BQ, B_);
    hipLaunchKernelGGL(flash_attn_kernel, grid, dim3(NTHR), 0, stream,
                       q, k, v, mask, flag, out);
}